// Round 11
// baseline (223.769 us; speedup 1.0000x reference)
//
#include <hip/hip_runtime.h>
#include <stdint.h>

typedef float  v4f  __attribute__((ext_vector_type(4)));
typedef int    v4i  __attribute__((ext_vector_type(4)));
typedef __bf16 v8bf __attribute__((ext_vector_type(8)));
typedef __bf16 v4bf __attribute__((ext_vector_type(4)));

#define BATCH  2
#define NQ     4096
#define MK     1024
#define DMODEL 512
#define DCTX   768
#define NH     8
#define DH     64

// Merged prep: blocks [0,2816) convert x/ctx fp32->bf16 (RNE -> bits identical
// to inline-cvt GEMM path); blocks [2816,4352) transpose weights to
// Wt[512][K] bf16. Block 2816 zero-inits scal.
__global__ __launch_bounds__(256) void k_prep(
    const float* __restrict__ x, const float* __restrict__ ctx,
    __bf16* __restrict__ xb, __bf16* __restrict__ cb,
    const float* __restrict__ Wq, const float* __restrict__ Wk,
    const float* __restrict__ Wv, const float* __restrict__ Wo,
    __bf16* __restrict__ Wq_t, __bf16* __restrict__ Wk_t,
    __bf16* __restrict__ Wv_t, __bf16* __restrict__ Wo_t,
    unsigned* __restrict__ scal) {
  int bx = blockIdx.x;
  if (bx < 2816) {
    const int XC = BATCH * NQ * DMODEL / 8;
    const int CC = BATCH * MK * DCTX / 8;
    int idx = bx * 256 + threadIdx.x;
    const float* src; __bf16* dst;
    if (idx < XC) { src = x + (size_t)idx * 8; dst = xb + (size_t)idx * 8; }
    else {
      int j = idx - XC;
      if (j >= CC) return;
      src = ctx + (size_t)j * 8; dst = cb + (size_t)j * 8;
    }
    float4 a = *(const float4*)src, b = *(const float4*)(src + 4);
    v8bf o = { (__bf16)a.x, (__bf16)a.y, (__bf16)a.z, (__bf16)a.w,
               (__bf16)b.x, (__bf16)b.y, (__bf16)b.z, (__bf16)b.w };
    *(v8bf*)dst = o;
    return;
  }
  int id = bx - 2816;
  if (id == 0 && threadIdx.x < 4) scal[threadIdx.x] = 0u;
  int tx = id & 15, rem = id >> 4;
  int ty = rem % 24, tz = rem / 24;
  const float* src; __bf16* dst; int K;
  switch (tz) {
    case 0:  src = Wq; dst = Wq_t; K = DMODEL; break;
    case 1:  src = Wk; dst = Wk_t; K = DCTX;   break;
    case 2:  src = Wv; dst = Wv_t; K = DCTX;   break;
    default: src = Wo; dst = Wo_t; K = DMODEL; break;
  }
  int k0 = ty * 32;
  if (k0 >= K) return;
  int n0 = tx * 32;
  __shared__ __bf16 tile[32][33];
  int c = threadIdx.x & 31, r0 = threadIdx.x >> 5;
  for (int i = 0; i < 4; ++i) {
    int r = r0 + i * 8;
    tile[c][r] = (__bf16)src[(size_t)(k0 + r) * DMODEL + n0 + c];
  }
  __syncthreads();
  for (int i = 0; i < 4; ++i) {
    int r = r0 + i * 8;
    dst[(size_t)(n0 + r) * K + k0 + c] = tile[r][c];
  }
}

// B-stationary GEMM body (r7/r8-proven config; r10 BK-staging reverted):
// C tile = A[256 rows][K_] @ Bt[NC cols][K_]^T. 64 rows/wave (AF=4) -> 16
// MFMAs per 4 A-loads at NC=64. AD=4 A register prefetch; NC-col B panel for
// ALL K in LDS (one barrier); K-loop barrier-free; double-buffered B
// ds_reads; statically indexed (rule #20).
// Per-element k-ascending MFMA chain identical for any NC -> bit-identical C.
template<int K_, int NC, bool BIAS, bool AMAX>
__device__ __forceinline__ void gemm_body(
    char* smemraw, const __bf16* __restrict__ A, const __bf16* __restrict__ Bt,
    float* __restrict__ C, int N, int rowBlk, int colBlk,
    const float* __restrict__ bias,
    unsigned* __restrict__ amaxLo, unsigned* __restrict__ amaxHi) {
  constexpr int CS = K_ + 8;
  constexpr int GPC = K_ / 8;
  constexpr int JT = NC / 16;
  constexpr int NIT = K_ / 32;
  constexpr int AD = 4;  // A prefetch depth
  constexpr int AF = 4;  // row fragments per wave (64 rows)
  __bf16* Bs = (__bf16*)smemraw;
  float* redmax = (float*)(smemraw + (size_t)NC * CS * 2);
  const int tid = threadIdx.x;
  const int lane = tid & 63, wave = tid >> 6;
  const int l15 = lane & 15, g = lane >> 4;
  const int col0 = colBlk * NC;
  const int row0w = rowBlk * 256 + wave * 64;

#pragma unroll
  for (int i = 0; i < NC * GPC / 256; ++i) {
    int f = i * 256 + tid;
    int c = f / GPC, w = f - c * GPC;
    *(v8bf*)(&Bs[c * CS + w * 8]) =
        *(const v8bf*)(Bt + (size_t)(col0 + c) * K_ + w * 8);
  }

  const __bf16* ap[AF];
#pragma unroll
  for (int f = 0; f < AF; ++f)
    ap[f] = A + (size_t)(row0w + f * 16 + l15) * K_ + g * 8;

  // prologue A prefetch: independent of LDS, overlaps the staging barrier
  v8bf abuf[AF][AD];
#pragma unroll
  for (int i = 0; i < AD; ++i)
#pragma unroll
    for (int f = 0; f < AF; ++f)
      abuf[f][i] = *(const v8bf*)(ap[f] + i * 32);
  __syncthreads();

  v8bf bbuf[2][JT];
#pragma unroll
  for (int j = 0; j < JT; ++j)
    bbuf[0][j] = *(const v8bf*)(&Bs[(j * 16 + l15) * CS + g * 8]);

  v4f acc[AF][JT] = {};
#pragma unroll
  for (int it = 0; it < NIT; ++it) {
    const int cur = it & 1, nxt = cur ^ 1;
    if (it + 1 < NIT) {
#pragma unroll
      for (int j = 0; j < JT; ++j)
        bbuf[nxt][j] =
            *(const v8bf*)(&Bs[(j * 16 + l15) * CS + (it + 1) * 32 + g * 8]);
    }
    v8bf af[AF];
#pragma unroll
    for (int f = 0; f < AF; ++f) {
      af[f] = abuf[f][it % AD];
      if (it + AD < NIT)  // refill slot for iteration it+AD
        abuf[f][it % AD] = *(const v8bf*)(ap[f] + (it + AD) * 32);
    }
#pragma unroll
    for (int f = 0; f < AF; ++f)
#pragma unroll
      for (int j = 0; j < JT; ++j)
        acc[f][j] = __builtin_amdgcn_mfma_f32_16x16x32_bf16(
            af[f], bbuf[cur][j], acc[f][j], 0, 0, 0);
  }

  float lmax = 0.0f;
#pragma unroll
  for (int j = 0; j < JT; ++j) {
    int col = col0 + j * 16 + l15;
    float bv = BIAS ? bias[col] : 0.0f;
#pragma unroll
    for (int f = 0; f < AF; ++f) {
#pragma unroll
      for (int r = 0; r < 4; ++r) {
        int row = row0w + f * 16 + g * 4 + r;  // C/D: col=lane&15, row=quad*4+reg
        float cv = acc[f][j][r] + bv;
        C[(size_t)row * N + col] = cv;
        if (AMAX) lmax = fmaxf(lmax, fabsf(cv));
      }
    }
  }
  if (AMAX) {
    for (int off = 32; off > 0; off >>= 1)
      lmax = fmaxf(lmax, __shfl_xor(lmax, off, 64));
    if (lane == 0) redmax[wave] = lmax;
    __syncthreads();
    if (tid == 0) {
      float bm = fmaxf(fmaxf(redmax[0], redmax[1]), fmaxf(redmax[2], redmax[3]));
      atomicMax(col0 < 512 ? amaxLo : amaxHi, __float_as_uint(bm));
    }
  }
}

// Fused projections, XCD-aware (r2, proven on FETCH).
// blocks [0,256) = q GEMM (8192x512: 32 rowBlks x 8 colBlks @ NC=64);
// [256,512) = kv GEMM (2048x1024: 8 rowBlks x 32 colBlks @ NC=32 --
// r6/r10 bracket: NC=32 single-stage is the kv local optimum).
__global__ __launch_bounds__(256, 2) void k_gemm_qkv(
    const __bf16* __restrict__ xb, const __bf16* __restrict__ Wq_t,
    float* __restrict__ qf,
    const __bf16* __restrict__ cb, const __bf16* __restrict__ Wkv_t,
    float* __restrict__ kvf, unsigned* __restrict__ scal) {
  __shared__ __align__(16) char smem[64 * (512 + 8) * 2 + 16];
  int bid = blockIdx.x;
  if (bid < 256) {
    int xcd = bid & 7, w = bid >> 3;   // w in [0,32)
    gemm_body<512, 64, false, true>(smem, xb, Wq_t, qf, 512,
                                    xcd * 4 + (w >> 3), w & 7, nullptr,
                                    scal + 0, scal + 0);
  } else {
    int id = bid - 256;                // 256%8==0 -> id%8 == bid%8
    int xcd = id & 7, w = id >> 3;     // w in [0,32)
    gemm_body<768, 32, false, true>(smem, cb, Wkv_t, kvf, 1024,
                                    xcd, w, nullptr,
                                    scal + 1, scal + 2);
  }
}

// 256 blocks: 32 rowBlks x 8 colBlks @ NC=64 (4 rowBlks/XCD).
__global__ __launch_bounds__(256, 2) void k_gemm_out(
    const __bf16* __restrict__ o, const __bf16* __restrict__ Wo_t,
    float* __restrict__ out, const float* __restrict__ bo) {
  __shared__ __align__(16) char smem[64 * (512 + 8) * 2 + 16];
  int xcd = blockIdx.x & 7, w = blockIdx.x >> 3;
  gemm_body<512, 64, true, false>(smem, o, Wo_t, out, 512,
                                  xcd * 4 + (w >> 3), w & 7, bo,
                                  nullptr, nullptr);
}

// k/v quantization: blocks [0,1024) quantize k; [1024,1280) transpose-quantize v.
__global__ __launch_bounds__(256) void k_quant_kv(
    const float* __restrict__ kvf,
    int8_t* __restrict__ k8, int8_t* __restrict__ v8t,
    const unsigned* __restrict__ scal) {
  __shared__ int8_t tile[64][80];
  int bx = blockIdx.x;
  if (bx < 1024) {
    int j = bx * 256 + threadIdx.x;
    int r = j >> 7;
    int c4 = (j & 127) << 2;
    float4 v = *(const float4*)(kvf + (size_t)r * 1024 + c4);
    float s = 127.0f / __uint_as_float(scal[1]);
    int a0 = __float2int_rn(v.x * s), a1 = __float2int_rn(v.y * s);
    int a2 = __float2int_rn(v.z * s), a3 = __float2int_rn(v.w * s);
    a0 = max(-128, min(127, a0)); a1 = max(-128, min(127, a1));
    a2 = max(-128, min(127, a2)); a3 = max(-128, min(127, a3));
    unsigned p = (unsigned)(a0 & 255) | ((unsigned)(a1 & 255) << 8) |
                 ((unsigned)(a2 & 255) << 16) | ((unsigned)(a3 & 255) << 24);
    *(unsigned*)(k8 + (size_t)j * 4) = p;
    return;
  }
  int id = bx - 1024;
  int bh = id >> 4, b = bh >> 3, h = bh & 7;
  int j0 = (id & 15) * 64;
  const float s = 127.0f / __uint_as_float(scal[2]);
  int t = threadIdx.x;
  int j = t >> 2, dh0 = (t & 3) << 4;
  const float* src = kvf + (size_t)(b * MK + j0 + j) * 1024 + 512 + h * DH + dh0;
#pragma unroll
  for (int i = 0; i < 16; i += 4) {
    float4 v = *(const float4*)(src + i);
    int a0 = __float2int_rn(v.x * s), a1 = __float2int_rn(v.y * s);
    int a2 = __float2int_rn(v.z * s), a3 = __float2int_rn(v.w * s);
    tile[dh0 + i + 0][j] = (int8_t)max(-128, min(127, a0));
    tile[dh0 + i + 1][j] = (int8_t)max(-128, min(127, a1));
    tile[dh0 + i + 2][j] = (int8_t)max(-128, min(127, a2));
    tile[dh0 + i + 3][j] = (int8_t)max(-128, min(127, a3));
  }
  __syncthreads();
  int dh = t >> 2, jb = (t & 3) << 4;
  v4i val = *(const v4i*)(&tile[dh][jb]);
  *(v4i*)(v8t + (size_t)(bh * DH + dh) * MK + j0 + jb) = val;
}

__device__ __forceinline__ v4i quant_pack16(const float* p, float s) {
  v4i out;
#pragma unroll
  for (int q = 0; q < 4; ++q) {
    float4 v = *(const float4*)(p + q * 4);
    int a0 = __float2int_rn(v.x * s), a1 = __float2int_rn(v.y * s);
    int a2 = __float2int_rn(v.z * s), a3 = __float2int_rn(v.w * s);
    a0 = max(-128, min(127, a0)); a1 = max(-128, min(127, a1));
    a2 = max(-128, min(127, a2)); a3 = max(-128, min(127, a3));
    out[q] = (int)((unsigned)(a0 & 255) | ((unsigned)(a1 & 255) << 8) |
                   ((unsigned)(a2 & 255) << 16) | ((unsigned)(a3 & 255) << 24));
  }
  return out;
}

// pass 1 (r11): K slice (64 KB per b,h) is L2-resident and reused by 64
// blocks -> LDS staging was pure overhead (guide m169 pattern). kfrag is
// read DIRECTLY from global (64B-contiguous per row, L2-hit); the tile loop
// has ZERO barriers and pass LDS shrinks to the 16B reduction scratch.
// Same bytes to the same MFMAs in the same order -> bit-identical invz.
__global__ __launch_bounds__(256, 4) void k_pass1(
    const float* __restrict__ qf, int8_t* __restrict__ q8,
    const int8_t* __restrict__ k8,
    float* __restrict__ invz, unsigned* __restrict__ scal) {
  __shared__ float mared[4];
  int bh = blockIdx.y, b = bh >> 3, h = bh & 7;
  int wave = threadIdx.x >> 6, lane = threadIdx.x & 63;
  int l15 = lane & 15, g = lane >> 4;
  int row0 = blockIdx.x * 64;
  int myrow = row0 + wave * 16 + l15;
  const float aq = __uint_as_float(scal[0]), ak = __uint_as_float(scal[1]);
  const float alpha2 = (aq * ak) * (0.125f / (127.0f * 127.0f)) * 1.44269504f;
  const float sq = 127.0f / aq;
  const v4i z4 = {0, 0, 0, 0};
  size_t qoff = (size_t)(b * NQ + myrow) * DMODEL + h * DH + g * 16;
  v4i qfrag = quant_pack16(qf + qoff, sq);
  *(v4i*)(q8 + qoff) = qfrag;
  // lane's K base: row l15, cols g*16..g*16+15 of the (b,h) slice
  const int8_t* kf0 = k8 + (size_t)b * MK * DMODEL + h * DH +
                      (size_t)l15 * DMODEL + g * 16;

  float z[4] = {0.f, 0.f, 0.f, 0.f};
  int mi = -(1 << 30);
  for (int tile = 0; tile < 8; ++tile) {
    float zt = z[tile >> 1];
#pragma unroll
    for (int t = 0; t < 8; ++t) {
      v4i kfrag = *(const v4i*)(kf0 + (size_t)(tile * 128 + t * 16) * DMODEL);
      v4i sa = __builtin_amdgcn_mfma_i32_16x16x64_i8(kfrag, qfrag, z4, 0, 0, 0);
      mi = max(mi, max(max(sa[0], sa[1]), max(sa[2], sa[3])));
      float e0 = __builtin_amdgcn_exp2f((float)sa[0] * alpha2);
      float e1 = __builtin_amdgcn_exp2f((float)sa[1] * alpha2);
      float e2 = __builtin_amdgcn_exp2f((float)sa[2] * alpha2);
      float e3 = __builtin_amdgcn_exp2f((float)sa[3] * alpha2);
      zt += (e0 + e1) + (e2 + e3);
    }
    z[tile >> 1] = zt;
  }
#pragma unroll
  for (int i = 0; i < 4; ++i) {
    z[i] += __shfl_xor(z[i], 16, 64);
    z[i] += __shfl_xor(z[i], 32, 64);
  }
  mi = max(mi, __shfl_xor(mi, 16, 64));
  mi = max(mi, __shfl_xor(mi, 32, 64));
  float zt = (z[0] + z[1]) + (z[2] + z[3]);
  float iz = 1.0f / zt;
  if (g == 0) invz[(size_t)bh * NQ + myrow] = iz;
  float ma = __builtin_amdgcn_exp2f((float)mi * alpha2) * iz;
#pragma unroll
  for (int off = 1; off < 16; off <<= 1)
    ma = fmaxf(ma, __shfl_xor(ma, off, 64));
  if (lane == 0) mared[wave] = ma;
  __syncthreads();
  if (threadIdx.x == 0)
    atomicMax(scal + 3,
              __float_as_uint(fmaxf(fmaxf(mared[0], mared[1]),
                                    fmaxf(mared[2], mared[3]))));
}

// pass 2 (r11): K and V read directly from global (both L2-resident, m169
// pattern) -> ZERO LDS, ZERO barriers; waves run free (better MFMA/VALU pipe
// mixing across 16 waves/CU). In-register 4x4 lane-group transpose (r8).
// Same bytes to the same MFMAs in the same order -> bit-identical output.
__global__ __launch_bounds__(256, 4) void k_pass2(
    const int8_t* __restrict__ q8, const int8_t* __restrict__ k8,
    const int8_t* __restrict__ v8t, const float* __restrict__ invz,
    const unsigned* __restrict__ scal, __bf16* __restrict__ o) {
  int bh = blockIdx.y, b = bh >> 3, h = bh & 7;
  int wave = threadIdx.x >> 6, lane = threadIdx.x & 63;
  int l15 = lane & 15, g = lane >> 4;
  int row0 = blockIdx.x * 64;
  int myrow = row0 + wave * 16 + l15;
  const float aq = __uint_as_float(scal[0]), ak = __uint_as_float(scal[1]);
  const float avv = __uint_as_float(scal[2]), izm = __uint_as_float(scal[3]);
  const float alpha2 = (aq * ak) * (0.125f / (127.0f * 127.0f)) * 1.44269504f;
  const float oscale = (izm / 127.0f) * (avv / 127.0f);
  const float MAGIC = 12582912.0f;  // 1.5 * 2^23
  const v4i z4 = {0, 0, 0, 0};

  v4i qfrag = *(const v4i*)(q8 + (size_t)(b * NQ + myrow) * DMODEL + h * DH + g * 16);
  const float lcr = __builtin_amdgcn_logf(invz[(size_t)bh * NQ + myrow] * (127.0f / izm));
  // lane's K base: row l15, cols g*16..+15; V base: dim-row l15, key-col g*16
  const int8_t* kf0 = k8 + (size_t)b * MK * DMODEL + h * DH +
                      (size_t)l15 * DMODEL + g * 16;
  const int8_t* vf0 = v8t + (size_t)bh * DH * MK + (size_t)l15 * MK + g * 16;

  v4i pacc[4] = {};
  for (int tile = 0; tile < 8; ++tile) {
    int w[8];
#pragma unroll
    for (int t = 0; t < 8; ++t) {
      v4i kfrag = *(const v4i*)(kf0 + (size_t)(tile * 128 + t * 16) * DMODEL);
      v4i sa = __builtin_amdgcn_mfma_i32_16x16x64_i8(kfrag, qfrag, z4, 0, 0, 0);
      float f0 = __builtin_amdgcn_exp2f(fmaf((float)sa[0], alpha2, lcr)) + MAGIC;
      float f1 = __builtin_amdgcn_exp2f(fmaf((float)sa[1], alpha2, lcr)) + MAGIC;
      float f2 = __builtin_amdgcn_exp2f(fmaf((float)sa[2], alpha2, lcr)) + MAGIC;
      float f3 = __builtin_amdgcn_exp2f(fmaf((float)sa[3], alpha2, lcr)) + MAGIC;
      w[t] = (int)((__float_as_uint(f0) & 255u) |
                   ((__float_as_uint(f1) & 255u) << 8) |
                   ((__float_as_uint(f2) & 255u) << 16) |
                   (__float_as_uint(f3) << 24));
    }
    // in-register 4x4 lane-group transpose (r8-verified)
#pragma unroll
    for (int c = 0; c < 2; ++c) {
      int wc0 = w[c * 4 + 0], wc1 = w[c * 4 + 1];
      int wc2 = w[c * 4 + 2], wc3 = w[c * 4 + 3];
      int t0 = (g & 1) ? wc0 : wc1;
      int r0 = __shfl_xor(t0, 16, 64);
      int t1 = (g & 1) ? wc2 : wc3;
      int r1 = __shfl_xor(t1, 16, 64);
      int a0 = (g & 1) ? r0 : wc0;
      int a1 = (g & 1) ? wc1 : r0;
      int a2 = (g & 1) ? r1 : wc2;
      int a3 = (g & 1) ? wc3 : r1;
      int u0 = (g & 2) ? a0 : a2;
      int s0 = __shfl_xor(u0, 32, 64);
      int u1 = (g & 2) ? a1 : a3;
      int s1 = __shfl_xor(u1, 32, 64);
      v4i afrag;
      afrag[0] = (g & 2) ? s0 : a0;
      afrag[1] = (g & 2) ? s1 : a1;
      afrag[2] = (g & 2) ? a2 : s0;
      afrag[3] = (g & 2) ? a3 : s1;
#pragma unroll
      for (int d = 0; d < 4; ++d) {
        v4i vfrag = *(const v4i*)(vf0 + (size_t)(d * 16) * MK + tile * 128 + c * 64);
        pacc[d] = __builtin_amdgcn_mfma_i32_16x16x64_i8(vfrag, afrag, pacc[d], 0, 0, 0);
      }
    }
  }
  // D: col(l15)=qrow, row(g*4+r)=dim-within-16 -> 4 consecutive dims per lane
  __bf16* obase = o + (size_t)(b * NQ + row0 + wave * 16 + l15) * DMODEL + h * DH;
#pragma unroll
  for (int d = 0; d < 4; ++d) {
    v4bf ov;
#pragma unroll
    for (int r = 0; r < 4; ++r)
      ov[r] = (__bf16)((float)pacc[d][r] * oscale);
    *(v4bf*)(obase + d * 16 + g * 4) = ov;
  }
}

extern "C" void kernel_launch(void* const* d_in, const int* in_sizes, int n_in,
                              void* d_out, int out_size, void* d_ws, size_t ws_size,
                              hipStream_t stream) {
  (void)in_sizes; (void)n_in; (void)out_size; (void)ws_size;
  const float* x   = (const float*)d_in[0];
  const float* ctx = (const float*)d_in[1];
  const float* Wq  = (const float*)d_in[2];
  const float* Wk  = (const float*)d_in[3];
  const float* Wv  = (const float*)d_in[4];
  const float* Wo  = (const float*)d_in[5];
  const float* bo  = (const float*)d_in[6];
  float* out = (float*)d_out;

  char* ws = (char*)d_ws;
  size_t off = 0;
  auto alloc = [&](size_t bytes) {
    char* p = ws + off;
    off += (bytes + 255) & ~(size_t)255;
    return p;
  };
  unsigned* scal = (unsigned*)alloc(16);
  __bf16* Wq_t = (__bf16*)alloc((size_t)512 * 512 * 2);
  __bf16* Wk_t = (__bf16*)alloc((size_t)512 * 768 * 2);  // contiguous with Wv_t
  __bf16* Wv_t = (__bf16*)alloc((size_t)512 * 768 * 2);
  __bf16* Wo_t = (__bf16*)alloc((size_t)512 * 512 * 2);
  __bf16* xb   = (__bf16*)alloc((size_t)BATCH * NQ * DMODEL * 2);
  __bf16* cb   = (__bf16*)alloc((size_t)BATCH * MK * DCTX * 2);
  float* qf  = (float*)alloc((size_t)BATCH * NQ * DMODEL * 4);   // later reused as o
  float* kvf = (float*)alloc((size_t)BATCH * MK * 1024 * 4);     // [2048][1024]: k | v
  int8_t* q8 = (int8_t*)alloc((size_t)BATCH * NQ * DMODEL);
  int8_t* k8 = (int8_t*)alloc((size_t)BATCH * MK * DMODEL);
  int8_t* v8t = (int8_t*)alloc((size_t)BATCH * NH * DH * MK);
  float* invz = (float*)alloc((size_t)BATCH * NH * NQ * 4);
  __bf16* o = (__bf16*)qf;  // q_f32 dead after pass1 quantizes it

  k_prep<<<4352, 256, 0, stream>>>(x, ctx, xb, cb, Wq, Wk, Wv, Wo,
                                   Wq_t, Wk_t, Wv_t, Wo_t, scal);
  k_gemm_qkv<<<512, 256, 0, stream>>>(xb, Wq_t, qf, cb, Wk_t, kvf, scal);
  k_quant_kv<<<1280, 256, 0, stream>>>(kvf, k8, v8t, scal);
  k_pass1<<<dim3(64, 16), 256, 0, stream>>>(qf, q8, k8, invz, scal);
  k_pass2<<<dim3(64, 16), 256, 0, stream>>>(q8, k8, v8t, invz, scal, o);
  k_gemm_out<<<256, 256, 0, stream>>>(o, Wo_t, out, bo);
}

// Round 12
// 169.681 us; speedup vs baseline: 1.3188x; 1.3188x over previous
//
#include <hip/hip_runtime.h>
#include <stdint.h>

typedef float  v4f  __attribute__((ext_vector_type(4)));
typedef int    v4i  __attribute__((ext_vector_type(4)));
typedef __bf16 v8bf __attribute__((ext_vector_type(8)));
typedef __bf16 v4bf __attribute__((ext_vector_type(4)));

#define BATCH  2
#define NQ     4096
#define MK     1024
#define DMODEL 512
#define DCTX   768
#define NH     8
#define DH     64

// Merged prep: blocks [0,2816) convert x/ctx fp32->bf16 (RNE -> bits identical
// to inline-cvt GEMM path); blocks [2816,4352) transpose weights to
// Wt[512][K] bf16. Block 2816 zero-inits scal.
__global__ __launch_bounds__(256) void k_prep(
    const float* __restrict__ x, const float* __restrict__ ctx,
    __bf16* __restrict__ xb, __bf16* __restrict__ cb,
    const float* __restrict__ Wq, const float* __restrict__ Wk,
    const float* __restrict__ Wv, const float* __restrict__ Wo,
    __bf16* __restrict__ Wq_t, __bf16* __restrict__ Wk_t,
    __bf16* __restrict__ Wv_t, __bf16* __restrict__ Wo_t,
    unsigned* __restrict__ scal) {
  int bx = blockIdx.x;
  if (bx < 2816) {
    const int XC = BATCH * NQ * DMODEL / 8;
    const int CC = BATCH * MK * DCTX / 8;
    int idx = bx * 256 + threadIdx.x;
    const float* src; __bf16* dst;
    if (idx < XC) { src = x + (size_t)idx * 8; dst = xb + (size_t)idx * 8; }
    else {
      int j = idx - XC;
      if (j >= CC) return;
      src = ctx + (size_t)j * 8; dst = cb + (size_t)j * 8;
    }
    float4 a = *(const float4*)src, b = *(const float4*)(src + 4);
    v8bf o = { (__bf16)a.x, (__bf16)a.y, (__bf16)a.z, (__bf16)a.w,
               (__bf16)b.x, (__bf16)b.y, (__bf16)b.z, (__bf16)b.w };
    *(v8bf*)dst = o;
    return;
  }
  int id = bx - 2816;
  if (id == 0 && threadIdx.x < 4) scal[threadIdx.x] = 0u;
  int tx = id & 15, rem = id >> 4;
  int ty = rem % 24, tz = rem / 24;
  const float* src; __bf16* dst; int K;
  switch (tz) {
    case 0:  src = Wq; dst = Wq_t; K = DMODEL; break;
    case 1:  src = Wk; dst = Wk_t; K = DCTX;   break;
    case 2:  src = Wv; dst = Wv_t; K = DCTX;   break;
    default: src = Wo; dst = Wo_t; K = DMODEL; break;
  }
  int k0 = ty * 32;
  if (k0 >= K) return;
  int n0 = tx * 32;
  __shared__ __bf16 tile[32][33];
  int c = threadIdx.x & 31, r0 = threadIdx.x >> 5;
  for (int i = 0; i < 4; ++i) {
    int r = r0 + i * 8;
    tile[c][r] = (__bf16)src[(size_t)(k0 + r) * DMODEL + n0 + c];
  }
  __syncthreads();
  for (int i = 0; i < 4; ++i) {
    int r = r0 + i * 8;
    dst[(size_t)(n0 + r) * K + k0 + c] = tile[r][c];
  }
}

// B-stationary GEMM body (r7-proven config): C tile = A[256 rows][K_] @
// Bt[NC cols][K_]^T. 64 rows/wave (AF=4) -> 16 MFMAs per 4 A-loads at NC=64.
// AD=4 A register prefetch; NC-col B panel for ALL K in LDS (one barrier);
// K-loop barrier-free; double-buffered B ds_reads; statically indexed.
// Per-element k-ascending MFMA chain identical for any NC -> bit-identical C.
template<int K_, int NC, bool BIAS, bool AMAX>
__device__ __forceinline__ void gemm_body(
    char* smemraw, const __bf16* __restrict__ A, const __bf16* __restrict__ Bt,
    float* __restrict__ C, int N, int rowBlk, int colBlk,
    const float* __restrict__ bias,
    unsigned* __restrict__ amaxLo, unsigned* __restrict__ amaxHi) {
  constexpr int CS = K_ + 8;
  constexpr int GPC = K_ / 8;
  constexpr int JT = NC / 16;
  constexpr int NIT = K_ / 32;
  constexpr int AD = 4;  // A prefetch depth
  constexpr int AF = 4;  // row fragments per wave (64 rows)
  __bf16* Bs = (__bf16*)smemraw;
  float* redmax = (float*)(smemraw + (size_t)NC * CS * 2);
  const int tid = threadIdx.x;
  const int lane = tid & 63, wave = tid >> 6;
  const int l15 = lane & 15, g = lane >> 4;
  const int col0 = colBlk * NC;
  const int row0w = rowBlk * 256 + wave * 64;

#pragma unroll
  for (int i = 0; i < NC * GPC / 256; ++i) {
    int f = i * 256 + tid;
    int c = f / GPC, w = f - c * GPC;
    *(v8bf*)(&Bs[c * CS + w * 8]) =
        *(const v8bf*)(Bt + (size_t)(col0 + c) * K_ + w * 8);
  }

  const __bf16* ap[AF];
#pragma unroll
  for (int f = 0; f < AF; ++f)
    ap[f] = A + (size_t)(row0w + f * 16 + l15) * K_ + g * 8;

  // prologue A prefetch: independent of LDS, overlaps the staging barrier
  v8bf abuf[AF][AD];
#pragma unroll
  for (int i = 0; i < AD; ++i)
#pragma unroll
    for (int f = 0; f < AF; ++f)
      abuf[f][i] = *(const v8bf*)(ap[f] + i * 32);
  __syncthreads();

  v8bf bbuf[2][JT];
#pragma unroll
  for (int j = 0; j < JT; ++j)
    bbuf[0][j] = *(const v8bf*)(&Bs[(j * 16 + l15) * CS + g * 8]);

  v4f acc[AF][JT] = {};
#pragma unroll
  for (int it = 0; it < NIT; ++it) {
    const int cur = it & 1, nxt = cur ^ 1;
    if (it + 1 < NIT) {
#pragma unroll
      for (int j = 0; j < JT; ++j)
        bbuf[nxt][j] =
            *(const v8bf*)(&Bs[(j * 16 + l15) * CS + (it + 1) * 32 + g * 8]);
    }
    v8bf af[AF];
#pragma unroll
    for (int f = 0; f < AF; ++f) {
      af[f] = abuf[f][it % AD];
      if (it + AD < NIT)  // refill slot for iteration it+AD
        abuf[f][it % AD] = *(const v8bf*)(ap[f] + (it + AD) * 32);
    }
#pragma unroll
    for (int f = 0; f < AF; ++f)
#pragma unroll
      for (int j = 0; j < JT; ++j)
        acc[f][j] = __builtin_amdgcn_mfma_f32_16x16x32_bf16(
            af[f], bbuf[cur][j], acc[f][j], 0, 0, 0);
  }

  float lmax = 0.0f;
#pragma unroll
  for (int j = 0; j < JT; ++j) {
    int col = col0 + j * 16 + l15;
    float bv = BIAS ? bias[col] : 0.0f;
#pragma unroll
    for (int f = 0; f < AF; ++f) {
#pragma unroll
      for (int r = 0; r < 4; ++r) {
        int row = row0w + f * 16 + g * 4 + r;  // C/D: col=lane&15, row=quad*4+reg
        float cv = acc[f][j][r] + bv;
        C[(size_t)row * N + col] = cv;
        if (AMAX) lmax = fmaxf(lmax, fabsf(cv));
      }
    }
  }
  if (AMAX) {
    for (int off = 32; off > 0; off >>= 1)
      lmax = fmaxf(lmax, __shfl_xor(lmax, off, 64));
    if (lane == 0) redmax[wave] = lmax;
    __syncthreads();
    if (tid == 0) {
      float bm = fmaxf(fmaxf(redmax[0], redmax[1]), fmaxf(redmax[2], redmax[3]));
      atomicMax(col0 < 512 ? amaxLo : amaxHi, __float_as_uint(bm));
    }
  }
}

// Fused projections, XCD-aware (r2, proven on FETCH): all column-panels of
// one A row-panel land on the same XCD L2.
__global__ __launch_bounds__(256, 2) void k_gemm_qkv(
    const __bf16* __restrict__ xb, const __bf16* __restrict__ Wq_t,
    float* __restrict__ qf,
    const __bf16* __restrict__ cb, const __bf16* __restrict__ Wkv_t,
    float* __restrict__ kvf, unsigned* __restrict__ scal) {
  __shared__ __align__(16) char smem[64 * (512 + 8) * 2 + 16];
  int bid = blockIdx.x;
  if (bid < 256) {
    int xcd = bid & 7, w = bid >> 3;   // w in [0,32)
    gemm_body<512, 64, false, true>(smem, xb, Wq_t, qf, 512,
                                    xcd * 4 + (w >> 3), w & 7, nullptr,
                                    scal + 0, scal + 0);
  } else {
    int id = bid - 256;                // 256%8==0 -> id%8 == bid%8
    int xcd = id & 7, w = id >> 3;     // w in [0,32)
    gemm_body<768, 32, false, true>(smem, cb, Wkv_t, kvf, 1024,
                                    xcd, w, nullptr,
                                    scal + 1, scal + 2);
  }
}

// 256 blocks: 32 rowBlks x 8 colBlks @ NC=64 (4 rowBlks/XCD).
__global__ __launch_bounds__(256, 2) void k_gemm_out(
    const __bf16* __restrict__ o, const __bf16* __restrict__ Wo_t,
    float* __restrict__ out, const float* __restrict__ bo) {
  __shared__ __align__(16) char smem[64 * (512 + 8) * 2 + 16];
  int xcd = blockIdx.x & 7, w = blockIdx.x >> 3;
  gemm_body<512, 64, true, false>(smem, o, Wo_t, out, 512,
                                  xcd * 4 + (w >> 3), w & 7, bo,
                                  nullptr, nullptr);
}

// k/v quantization: blocks [0,1024) quantize k; [1024,1280) transpose-quantize v.
__global__ __launch_bounds__(256) void k_quant_kv(
    const float* __restrict__ kvf,
    int8_t* __restrict__ k8, int8_t* __restrict__ v8t,
    const unsigned* __restrict__ scal) {
  __shared__ int8_t tile[64][80];
  int bx = blockIdx.x;
  if (bx < 1024) {
    int j = bx * 256 + threadIdx.x;
    int r = j >> 7;
    int c4 = (j & 127) << 2;
    float4 v = *(const float4*)(kvf + (size_t)r * 1024 + c4);
    float s = 127.0f / __uint_as_float(scal[1]);
    int a0 = __float2int_rn(v.x * s), a1 = __float2int_rn(v.y * s);
    int a2 = __float2int_rn(v.z * s), a3 = __float2int_rn(v.w * s);
    a0 = max(-128, min(127, a0)); a1 = max(-128, min(127, a1));
    a2 = max(-128, min(127, a2)); a3 = max(-128, min(127, a3));
    unsigned p = (unsigned)(a0 & 255) | ((unsigned)(a1 & 255) << 8) |
                 ((unsigned)(a2 & 255) << 16) | ((unsigned)(a3 & 255) << 24);
    *(unsigned*)(k8 + (size_t)j * 4) = p;
    return;
  }
  int id = bx - 1024;
  int bh = id >> 4, b = bh >> 3, h = bh & 7;
  int j0 = (id & 15) * 64;
  const float s = 127.0f / __uint_as_float(scal[2]);
  int t = threadIdx.x;
  int j = t >> 2, dh0 = (t & 3) << 4;
  const float* src = kvf + (size_t)(b * MK + j0 + j) * 1024 + 512 + h * DH + dh0;
#pragma unroll
  for (int i = 0; i < 16; i += 4) {
    float4 v = *(const float4*)(src + i);
    int a0 = __float2int_rn(v.x * s), a1 = __float2int_rn(v.y * s);
    int a2 = __float2int_rn(v.z * s), a3 = __float2int_rn(v.w * s);
    tile[dh0 + i + 0][j] = (int8_t)max(-128, min(127, a0));
    tile[dh0 + i + 1][j] = (int8_t)max(-128, min(127, a1));
    tile[dh0 + i + 2][j] = (int8_t)max(-128, min(127, a2));
    tile[dh0 + i + 3][j] = (int8_t)max(-128, min(127, a3));
  }
  __syncthreads();
  int dh = t >> 2, jb = (t & 3) << 4;
  v4i val = *(const v4i*)(&tile[dh][jb]);
  *(v4i*)(v8t + (size_t)(bh * DH + dh) * MK + j0 + jb) = val;
}

__device__ __forceinline__ v4i quant_pack16(const float* p, float s) {
  v4i out;
#pragma unroll
  for (int q = 0; q < 4; ++q) {
    float4 v = *(const float4*)(p + q * 4);
    int a0 = __float2int_rn(v.x * s), a1 = __float2int_rn(v.y * s);
    int a2 = __float2int_rn(v.z * s), a3 = __float2int_rn(v.w * s);
    a0 = max(-128, min(127, a0)); a1 = max(-128, min(127, a1));
    a2 = max(-128, min(127, a2)); a3 = max(-128, min(127, a3));
    out[q] = (int)((unsigned)(a0 & 255) | ((unsigned)(a1 & 255) << 8) |
                   ((unsigned)(a2 & 255) << 16) | ((unsigned)(a3 & 255) << 24));
  }
  return out;
}

// pass 1 (r8-proven): double-buffered kbuf -> ONE barrier per tile; staging
// ds_writes moved to end of compute (overlap), global prefetch covered by
// full tile. z summation tree unchanged -> bit-identical invz.
__global__ __launch_bounds__(256, 4) void k_pass1(
    const float* __restrict__ qf, int8_t* __restrict__ q8,
    const int8_t* __restrict__ k8,
    float* __restrict__ invz, unsigned* __restrict__ scal) {
  __shared__ __align__(16) int8_t kbuf[2][128 * 72];
  __shared__ float mared[4];
  int bh = blockIdx.y, b = bh >> 3, h = bh & 7;
  int wave = threadIdx.x >> 6, lane = threadIdx.x & 63;
  int l15 = lane & 15, g = lane >> 4;
  int row0 = blockIdx.x * 64;
  int myrow = row0 + wave * 16 + l15;
  const float aq = __uint_as_float(scal[0]), ak = __uint_as_float(scal[1]);
  const float alpha2 = (aq * ak) * (0.125f / (127.0f * 127.0f)) * 1.44269504f;
  const float sq = 127.0f / aq;
  const v4i z4 = {0, 0, 0, 0};
  size_t qoff = (size_t)(b * NQ + myrow) * DMODEL + h * DH + g * 16;
  v4i qfrag = quant_pack16(qf + qoff, sq);
  *(v4i*)(q8 + qoff) = qfrag;
  const int8_t* kbase = k8 + (size_t)b * MK * DMODEL + h * DH;
  const int rs = threadIdx.x >> 2, qs = (threadIdx.x & 3) * 16;
  const int8_t* kls = kbase + (size_t)rs * DMODEL + qs;

  v4i kp0 = *(const v4i*)(kls);
  v4i kp1 = *(const v4i*)(kls + (size_t)64 * DMODEL);
  *(v4i*)(&kbuf[0][rs * 72 + qs]) = kp0;
  *(v4i*)(&kbuf[0][(rs + 64) * 72 + qs]) = kp1;

  float z[4] = {0.f, 0.f, 0.f, 0.f};
  int mi = -(1 << 30);
  for (int tile = 0; tile < 8; ++tile) {
    const int cur = tile & 1;
    __syncthreads();  // kbuf[cur] writes visible; prior reads of kbuf[cur^1] done
    if (tile < 7) {   // prefetch next tile; latency hides under compute below
      kp0 = *(const v4i*)(kls + (size_t)((tile + 1) * 128) * DMODEL);
      kp1 = *(const v4i*)(kls + (size_t)((tile + 1) * 128 + 64) * DMODEL);
    }
    float zt = z[tile >> 1];
#pragma unroll
    for (int t = 0; t < 8; ++t) {
      v4i kfrag = *(const v4i*)(&kbuf[cur][(t * 16 + l15) * 72 + g * 16]);
      v4i sa = __builtin_amdgcn_mfma_i32_16x16x64_i8(kfrag, qfrag, z4, 0, 0, 0);
      mi = max(mi, max(max(sa[0], sa[1]), max(sa[2], sa[3])));
      float e0 = __builtin_amdgcn_exp2f((float)sa[0] * alpha2);
      float e1 = __builtin_amdgcn_exp2f((float)sa[1] * alpha2);
      float e2 = __builtin_amdgcn_exp2f((float)sa[2] * alpha2);
      float e3 = __builtin_amdgcn_exp2f((float)sa[3] * alpha2);
      zt += (e0 + e1) + (e2 + e3);
    }
    z[tile >> 1] = zt;
    if (tile < 7) {   // write other buffer while peers still compute this one
      *(v4i*)(&kbuf[cur ^ 1][rs * 72 + qs]) = kp0;
      *(v4i*)(&kbuf[cur ^ 1][(rs + 64) * 72 + qs]) = kp1;
    }
  }
#pragma unroll
  for (int i = 0; i < 4; ++i) {
    z[i] += __shfl_xor(z[i], 16, 64);
    z[i] += __shfl_xor(z[i], 32, 64);
  }
  mi = max(mi, __shfl_xor(mi, 16, 64));
  mi = max(mi, __shfl_xor(mi, 32, 64));
  float zt = (z[0] + z[1]) + (z[2] + z[3]);
  float iz = 1.0f / zt;
  if (g == 0) invz[(size_t)bh * NQ + myrow] = iz;
  float ma = __builtin_amdgcn_exp2f((float)mi * alpha2) * iz;  // row softmax max
#pragma unroll
  for (int off = 1; off < 16; off <<= 1)
    ma = fmaxf(ma, __shfl_xor(ma, off, 64));
  if (lane == 0) mared[wave] = ma;
  __syncthreads();
  if (threadIdx.x == 0)
    atomicMax(scal + 3,
              __float_as_uint(fmaxf(fmaxf(mared[0], mared[1]),
                                    fmaxf(mared[2], mared[3]))));
}

// pass 2 (r8-proven): double-buffered kbuf+vbuf -> ONE barrier per tile; attn
// fragment exchange moved from LDS (albuf) to an in-register 4x4 lane-group
// transpose via shfl_xor (bytes identical -> bit-identical PV). LDS 37KB ->
// 4 blocks/CU retained. Exact int32 PV accumulation unchanged.
__global__ __launch_bounds__(256, 4) void k_pass2(
    const int8_t* __restrict__ q8, const int8_t* __restrict__ k8,
    const int8_t* __restrict__ v8t, const float* __restrict__ invz,
    const unsigned* __restrict__ scal, __bf16* __restrict__ o) {
  __shared__ __align__(16) int8_t kbuf[2][128 * 72];
  __shared__ __align__(16) int8_t vbuf[2][64 * 152];
  int bh = blockIdx.y, b = bh >> 3, h = bh & 7;
  int wave = threadIdx.x >> 6, lane = threadIdx.x & 63;
  int l15 = lane & 15, g = lane >> 4;
  int row0 = blockIdx.x * 64;
  int myrow = row0 + wave * 16 + l15;
  const float aq = __uint_as_float(scal[0]), ak = __uint_as_float(scal[1]);
  const float avv = __uint_as_float(scal[2]), izm = __uint_as_float(scal[3]);
  const float alpha2 = (aq * ak) * (0.125f / (127.0f * 127.0f)) * 1.44269504f;
  const float oscale = (izm / 127.0f) * (avv / 127.0f);
  const float MAGIC = 12582912.0f;  // 1.5 * 2^23
  const v4i z4 = {0, 0, 0, 0};

  v4i qfrag = *(const v4i*)(q8 + (size_t)(b * NQ + myrow) * DMODEL + h * DH + g * 16);
  const float lcr = __builtin_amdgcn_logf(invz[(size_t)bh * NQ + myrow] * (127.0f / izm));
  const int8_t* kbase = k8 + (size_t)b * MK * DMODEL + h * DH;
  const int8_t* vbase = v8t + (size_t)bh * DH * MK;
  const int rs = threadIdx.x >> 2, qs = (threadIdx.x & 3) * 16;
  const int vr = threadIdx.x >> 3, vq = (threadIdx.x & 7) * 16;
  const int8_t* kls = kbase + (size_t)rs * DMODEL + qs;
  const int8_t* vls = vbase + (size_t)vr * MK + vq;

  v4i kp0 = *(const v4i*)(kls);
  v4i kp1 = *(const v4i*)(kls + (size_t)64 * DMODEL);
  v4i vp0 = *(const v4i*)(vls);
  v4i vp1 = *(const v4i*)(vls + (size_t)32 * MK);
  *(v4i*)(&kbuf[0][rs * 72 + qs]) = kp0;
  *(v4i*)(&kbuf[0][(rs + 64) * 72 + qs]) = kp1;
  *(v4i*)(&vbuf[0][vr * 152 + vq]) = vp0;
  *(v4i*)(&vbuf[0][(vr + 32) * 152 + vq]) = vp1;

  v4i pacc[4] = {};
  for (int tile = 0; tile < 8; ++tile) {
    const int cur = tile & 1;
    __syncthreads();  // buf[cur] ready; peers' reads of buf[cur^1] retired
    if (tile < 7) {   // prefetch next tile; hides under QK^T + softmax + PV
      kp0 = *(const v4i*)(kls + (size_t)((tile + 1) * 128) * DMODEL);
      kp1 = *(const v4i*)(kls + (size_t)((tile + 1) * 128 + 64) * DMODEL);
      vp0 = *(const v4i*)(vls + (tile + 1) * 128);
      vp1 = *(const v4i*)(vls + (size_t)32 * MK + (tile + 1) * 128);
    }
    int w[8];
#pragma unroll
    for (int t = 0; t < 8; ++t) {
      v4i kfrag = *(const v4i*)(&kbuf[cur][(t * 16 + l15) * 72 + g * 16]);
      v4i sa = __builtin_amdgcn_mfma_i32_16x16x64_i8(kfrag, qfrag, z4, 0, 0, 0);
      float f0 = __builtin_amdgcn_exp2f(fmaf((float)sa[0], alpha2, lcr)) + MAGIC;
      float f1 = __builtin_amdgcn_exp2f(fmaf((float)sa[1], alpha2, lcr)) + MAGIC;
      float f2 = __builtin_amdgcn_exp2f(fmaf((float)sa[2], alpha2, lcr)) + MAGIC;
      float f3 = __builtin_amdgcn_exp2f(fmaf((float)sa[3], alpha2, lcr)) + MAGIC;
      w[t] = (int)((__float_as_uint(f0) & 255u) |
                   ((__float_as_uint(f1) & 255u) << 8) |
                   ((__float_as_uint(f2) & 255u) << 16) |
                   (__float_as_uint(f3) << 24));
    }
    // In-register 4x4 lane-group transpose (replaces albuf round-trip):
    // afrag[m] must be group-m's w[c*4+g]  (verified g=0 and g=1 traces).
#pragma unroll
    for (int c = 0; c < 2; ++c) {
      int wc0 = w[c * 4 + 0], wc1 = w[c * 4 + 1];
      int wc2 = w[c * 4 + 2], wc3 = w[c * 4 + 3];
      int t0 = (g & 1) ? wc0 : wc1;
      int r0 = __shfl_xor(t0, 16, 64);
      int t1 = (g & 1) ? wc2 : wc3;
      int r1 = __shfl_xor(t1, 16, 64);
      int a0 = (g & 1) ? r0 : wc0;
      int a1 = (g & 1) ? wc1 : r0;
      int a2 = (g & 1) ? r1 : wc2;
      int a3 = (g & 1) ? wc3 : r1;
      int u0 = (g & 2) ? a0 : a2;
      int s0 = __shfl_xor(u0, 32, 64);
      int u1 = (g & 2) ? a1 : a3;
      int s1 = __shfl_xor(u1, 32, 64);
      v4i afrag;
      afrag[0] = (g & 2) ? s0 : a0;
      afrag[1] = (g & 2) ? s1 : a1;
      afrag[2] = (g & 2) ? a2 : s0;
      afrag[3] = (g & 2) ? a3 : s1;
#pragma unroll
      for (int d = 0; d < 4; ++d) {
        v4i vfrag = *(const v4i*)(&vbuf[cur][(d * 16 + l15) * 152 + c * 64 + g * 16]);
        // swapped operands: D[dim][qrow] -> lane l15 = qrow, rows = dims
        pacc[d] = __builtin_amdgcn_mfma_i32_16x16x64_i8(vfrag, afrag, pacc[d], 0, 0, 0);
      }
    }
    if (tile < 7) {   // stage next tile into other buffer (overlaps peers' compute)
      *(v4i*)(&kbuf[cur ^ 1][rs * 72 + qs]) = kp0;
      *(v4i*)(&kbuf[cur ^ 1][(rs + 64) * 72 + qs]) = kp1;
      *(v4i*)(&vbuf[cur ^ 1][vr * 152 + vq]) = vp0;
      *(v4i*)(&vbuf[cur ^ 1][(vr + 32) * 152 + vq]) = vp1;
    }
  }
  // D: col(l15)=qrow, row(g*4+r)=dim-within-16 -> 4 consecutive dims per lane
  __bf16* obase = o + (size_t)(b * NQ + row0 + wave * 16 + l15) * DMODEL + h * DH;
#pragma unroll
  for (int d = 0; d < 4; ++d) {
    v4bf ov;
#pragma unroll
    for (int r = 0; r < 4; ++r)
      ov[r] = (__bf16)((float)pacc[d][r] * oscale);
    *(v4bf*)(obase + d * 16 + g * 4) = ov;
  }
}

extern "C" void kernel_launch(void* const* d_in, const int* in_sizes, int n_in,
                              void* d_out, int out_size, void* d_ws, size_t ws_size,
                              hipStream_t stream) {
  (void)in_sizes; (void)n_in; (void)out_size; (void)ws_size;
  const float* x   = (const float*)d_in[0];
  const float* ctx = (const float*)d_in[1];
  const float* Wq  = (const float*)d_in[2];
  const float* Wk  = (const float*)d_in[3];
  const float* Wv  = (const float*)d_in[4];
  const float* Wo  = (const float*)d_in[5];
  const float* bo  = (const float*)d_in[6];
  float* out = (float*)d_out;

  char* ws = (char*)d_ws;
  size_t off = 0;
  auto alloc = [&](size_t bytes) {
    char* p = ws + off;
    off += (bytes + 255) & ~(size_t)255;
    return p;
  };
  unsigned* scal = (unsigned*)alloc(16);
  __bf16* Wq_t = (__bf16*)alloc((size_t)512 * 512 * 2);
  __bf16* Wk_t = (__bf16*)alloc((size_t)512 * 768 * 2);  // contiguous with Wv_t
  __bf16* Wv_t = (__bf16*)alloc((size_t)512 * 768 * 2);
  __bf16* Wo_t = (__bf16*)alloc((size_t)512 * 512 * 2);
  __bf16* xb   = (__bf16*)alloc((size_t)BATCH * NQ * DMODEL * 2);
  __bf16* cb   = (__bf16*)alloc((size_t)BATCH * MK * DCTX * 2);
  float* qf  = (float*)alloc((size_t)BATCH * NQ * DMODEL * 4);   // later reused as o
  float* kvf = (float*)alloc((size_t)BATCH * MK * 1024 * 4);     // [2048][1024]: k | v
  int8_t* q8 = (int8_t*)alloc((size_t)BATCH * NQ * DMODEL);
  int8_t* k8 = (int8_t*)alloc((size_t)BATCH * MK * DMODEL);
  int8_t* v8t = (int8_t*)alloc((size_t)BATCH * NH * DH * MK);
  float* invz = (float*)alloc((size_t)BATCH * NH * NQ * 4);
  __bf16* o = (__bf16*)qf;  // q_f32 dead after pass1 quantizes it

  k_prep<<<4352, 256, 0, stream>>>(x, ctx, xb, cb, Wq, Wk, Wv, Wo,
                                   Wq_t, Wk_t, Wv_t, Wo_t, scal);
  k_gemm_qkv<<<512, 256, 0, stream>>>(xb, Wq_t, qf, cb, Wk_t, kvf, scal);
  k_quant_kv<<<1280, 256, 0, stream>>>(kvf, k8, v8t, scal);
  k_pass1<<<dim3(64, 16), 256, 0, stream>>>(qf, q8, k8, invz, scal);
  k_pass2<<<dim3(64, 16), 256, 0, stream>>>(q8, k8, v8t, invz, scal, o);
  k_gemm_out<<<256, 256, 0, stream>>>(o, Wo_t, out, bo);
}

// Round 13
// 169.292 us; speedup vs baseline: 1.3218x; 1.0023x over previous
//
#include <hip/hip_runtime.h>
#include <stdint.h>

typedef float  v4f  __attribute__((ext_vector_type(4)));
typedef int    v4i  __attribute__((ext_vector_type(4)));
typedef __bf16 v8bf __attribute__((ext_vector_type(8)));
typedef __bf16 v4bf __attribute__((ext_vector_type(4)));

#define BATCH  2
#define NQ     4096
#define MK     1024
#define DMODEL 512
#define DCTX   768
#define NH     8
#define DH     64

// Merged prep: blocks [0,2816) convert x/ctx fp32->bf16 (RNE -> bits identical
// to inline-cvt GEMM path); blocks [2816,4352) transpose weights to
// Wt[512][K] bf16. Block 2816 zero-inits scal.
__global__ __launch_bounds__(256) void k_prep(
    const float* __restrict__ x, const float* __restrict__ ctx,
    __bf16* __restrict__ xb, __bf16* __restrict__ cb,
    const float* __restrict__ Wq, const float* __restrict__ Wk,
    const float* __restrict__ Wv, const float* __restrict__ Wo,
    __bf16* __restrict__ Wq_t, __bf16* __restrict__ Wk_t,
    __bf16* __restrict__ Wv_t, __bf16* __restrict__ Wo_t,
    unsigned* __restrict__ scal) {
  int bx = blockIdx.x;
  if (bx < 2816) {
    const int XC = BATCH * NQ * DMODEL / 8;
    const int CC = BATCH * MK * DCTX / 8;
    int idx = bx * 256 + threadIdx.x;
    const float* src; __bf16* dst;
    if (idx < XC) { src = x + (size_t)idx * 8; dst = xb + (size_t)idx * 8; }
    else {
      int j = idx - XC;
      if (j >= CC) return;
      src = ctx + (size_t)j * 8; dst = cb + (size_t)j * 8;
    }
    float4 a = *(const float4*)src, b = *(const float4*)(src + 4);
    v8bf o = { (__bf16)a.x, (__bf16)a.y, (__bf16)a.z, (__bf16)a.w,
               (__bf16)b.x, (__bf16)b.y, (__bf16)b.z, (__bf16)b.w };
    *(v8bf*)dst = o;
    return;
  }
  int id = bx - 2816;
  if (id == 0 && threadIdx.x < 4) scal[threadIdx.x] = 0u;
  int tx = id & 15, rem = id >> 4;
  int ty = rem % 24, tz = rem / 24;
  const float* src; __bf16* dst; int K;
  switch (tz) {
    case 0:  src = Wq; dst = Wq_t; K = DMODEL; break;
    case 1:  src = Wk; dst = Wk_t; K = DCTX;   break;
    case 2:  src = Wv; dst = Wv_t; K = DCTX;   break;
    default: src = Wo; dst = Wo_t; K = DMODEL; break;
  }
  int k0 = ty * 32;
  if (k0 >= K) return;
  int n0 = tx * 32;
  __shared__ __bf16 tile[32][33];
  int c = threadIdx.x & 31, r0 = threadIdx.x >> 5;
  for (int i = 0; i < 4; ++i) {
    int r = r0 + i * 8;
    tile[c][r] = (__bf16)src[(size_t)(k0 + r) * DMODEL + n0 + c];
  }
  __syncthreads();
  for (int i = 0; i < 4; ++i) {
    int r = r0 + i * 8;
    dst[(size_t)(n0 + r) * K + k0 + c] = tile[r][c];
  }
}

// B-stationary GEMM body (r13: AF now a template param). C tile =
// A[AF*64 rows][K_] @ Bt[NC cols][K_]^T. AF row-fragments/wave; at NC=64,
// MFMA:A-load density is 4:1 for any AF. AD=4 A register prefetch; NC-col
// B panel for ALL K in LDS (one barrier); K-loop barrier-free;
// double-buffered B ds_reads; statically indexed (rule #20).
// AF changes only which rows a wave owns -- each output element's
// k-ascending MFMA chain is unchanged -> bit-identical C.
template<int K_, int NC, int AF, bool BIAS, bool AMAX>
__device__ __forceinline__ void gemm_body(
    char* smemraw, const __bf16* __restrict__ A, const __bf16* __restrict__ Bt,
    float* __restrict__ C, int N, int rowBlk, int colBlk,
    const float* __restrict__ bias,
    unsigned* __restrict__ amaxLo, unsigned* __restrict__ amaxHi) {
  constexpr int CS = K_ + 8;
  constexpr int GPC = K_ / 8;
  constexpr int JT = NC / 16;
  constexpr int NIT = K_ / 32;
  constexpr int AD = 4;  // A prefetch depth
  __bf16* Bs = (__bf16*)smemraw;
  float* redmax = (float*)(smemraw + (size_t)NC * CS * 2);
  const int tid = threadIdx.x;
  const int lane = tid & 63, wave = tid >> 6;
  const int l15 = lane & 15, g = lane >> 4;
  const int col0 = colBlk * NC;
  const int row0w = rowBlk * (AF * 64) + wave * (AF * 16);

#pragma unroll
  for (int i = 0; i < NC * GPC / 256; ++i) {
    int f = i * 256 + tid;
    int c = f / GPC, w = f - c * GPC;
    *(v8bf*)(&Bs[c * CS + w * 8]) =
        *(const v8bf*)(Bt + (size_t)(col0 + c) * K_ + w * 8);
  }

  const __bf16* ap[AF];
#pragma unroll
  for (int f = 0; f < AF; ++f)
    ap[f] = A + (size_t)(row0w + f * 16 + l15) * K_ + g * 8;

  // prologue A prefetch: independent of LDS, overlaps the staging barrier
  v8bf abuf[AF][AD];
#pragma unroll
  for (int i = 0; i < AD; ++i)
#pragma unroll
    for (int f = 0; f < AF; ++f)
      abuf[f][i] = *(const v8bf*)(ap[f] + i * 32);
  __syncthreads();

  v8bf bbuf[2][JT];
#pragma unroll
  for (int j = 0; j < JT; ++j)
    bbuf[0][j] = *(const v8bf*)(&Bs[(j * 16 + l15) * CS + g * 8]);

  v4f acc[AF][JT] = {};
#pragma unroll
  for (int it = 0; it < NIT; ++it) {
    const int cur = it & 1, nxt = cur ^ 1;
    if (it + 1 < NIT) {
#pragma unroll
      for (int j = 0; j < JT; ++j)
        bbuf[nxt][j] =
            *(const v8bf*)(&Bs[(j * 16 + l15) * CS + (it + 1) * 32 + g * 8]);
    }
    v8bf af[AF];
#pragma unroll
    for (int f = 0; f < AF; ++f) {
      af[f] = abuf[f][it % AD];
      if (it + AD < NIT)  // refill slot for iteration it+AD
        abuf[f][it % AD] = *(const v8bf*)(ap[f] + (it + AD) * 32);
    }
#pragma unroll
    for (int f = 0; f < AF; ++f)
#pragma unroll
      for (int j = 0; j < JT; ++j)
        acc[f][j] = __builtin_amdgcn_mfma_f32_16x16x32_bf16(
            af[f], bbuf[cur][j], acc[f][j], 0, 0, 0);
  }

  float lmax = 0.0f;
#pragma unroll
  for (int j = 0; j < JT; ++j) {
    int col = col0 + j * 16 + l15;
    float bv = BIAS ? bias[col] : 0.0f;
#pragma unroll
    for (int f = 0; f < AF; ++f) {
#pragma unroll
      for (int r = 0; r < 4; ++r) {
        int row = row0w + f * 16 + g * 4 + r;  // C/D: col=lane&15, row=quad*4+reg
        float cv = acc[f][j][r] + bv;
        C[(size_t)row * N + col] = cv;
        if (AMAX) lmax = fmaxf(lmax, fabsf(cv));
      }
    }
  }
  if (AMAX) {
    for (int off = 32; off > 0; off >>= 1)
      lmax = fmaxf(lmax, __shfl_xor(lmax, off, 64));
    if (lane == 0) redmax[wave] = lmax;
    __syncthreads();
    if (tid == 0) {
      float bm = fmaxf(fmaxf(redmax[0], redmax[1]), fmaxf(redmax[2], redmax[3]));
      atomicMax(col0 < 512 ? amaxLo : amaxHi, __float_as_uint(bm));
    }
  }
}

// Fused projections, XCD-aware (r2, proven on FETCH): all column-panels of
// one A row-panel land on the same XCD L2. AF=4 (r7-proven; launch carries
// 512 blocks -> 2 blocks/CU during this kernel).
__global__ __launch_bounds__(256, 2) void k_gemm_qkv(
    const __bf16* __restrict__ xb, const __bf16* __restrict__ Wq_t,
    float* __restrict__ qf,
    const __bf16* __restrict__ cb, const __bf16* __restrict__ Wkv_t,
    float* __restrict__ kvf, unsigned* __restrict__ scal) {
  __shared__ __align__(16) char smem[64 * (512 + 8) * 2 + 16];
  int bid = blockIdx.x;
  if (bid < 256) {
    int xcd = bid & 7, w = bid >> 3;   // w in [0,32)
    gemm_body<512, 64, 4, false, true>(smem, xb, Wq_t, qf, 512,
                                       xcd * 4 + (w >> 3), w & 7, nullptr,
                                       scal + 0, scal + 0);
  } else {
    int id = bid - 256;                // 256%8==0 -> id%8 == bid%8
    int xcd = id & 7, w = id >> 3;     // w in [0,32)
    gemm_body<768, 32, 4, false, true>(smem, cb, Wkv_t, kvf, 1024,
                                       xcd, w, nullptr,
                                       scal + 1, scal + 2);
  }
}

// r13: AF=2 (128-row tile) -> 64 rowBlks x 8 colBlks = 512 blocks =
// 2 blocks/CU (was 256 blocks = 1/CU = 1 wave/SIMD, minimum TLP for a
// latency-bound kernel). A-load density unchanged at 4:1; per-element
// MFMA chain unchanged -> bit-identical. 8 rowBlks per XCD.
__global__ __launch_bounds__(256, 2) void k_gemm_out(
    const __bf16* __restrict__ o, const __bf16* __restrict__ Wo_t,
    float* __restrict__ out, const float* __restrict__ bo) {
  __shared__ __align__(16) char smem[64 * (512 + 8) * 2 + 16];
  int xcd = blockIdx.x & 7, w = blockIdx.x >> 3;  // w in [0,64)
  gemm_body<512, 64, 2, true, false>(smem, o, Wo_t, out, 512,
                                     xcd * 8 + (w >> 3), w & 7, bo,
                                     nullptr, nullptr);
}

// k/v quantization: blocks [0,1024) quantize k; [1024,1280) transpose-quantize v.
__global__ __launch_bounds__(256) void k_quant_kv(
    const float* __restrict__ kvf,
    int8_t* __restrict__ k8, int8_t* __restrict__ v8t,
    const unsigned* __restrict__ scal) {
  __shared__ int8_t tile[64][80];
  int bx = blockIdx.x;
  if (bx < 1024) {
    int j = bx * 256 + threadIdx.x;
    int r = j >> 7;
    int c4 = (j & 127) << 2;
    float4 v = *(const float4*)(kvf + (size_t)r * 1024 + c4);
    float s = 127.0f / __uint_as_float(scal[1]);
    int a0 = __float2int_rn(v.x * s), a1 = __float2int_rn(v.y * s);
    int a2 = __float2int_rn(v.z * s), a3 = __float2int_rn(v.w * s);
    a0 = max(-128, min(127, a0)); a1 = max(-128, min(127, a1));
    a2 = max(-128, min(127, a2)); a3 = max(-128, min(127, a3));
    unsigned p = (unsigned)(a0 & 255) | ((unsigned)(a1 & 255) << 8) |
                 ((unsigned)(a2 & 255) << 16) | ((unsigned)(a3 & 255) << 24);
    *(unsigned*)(k8 + (size_t)j * 4) = p;
    return;
  }
  int id = bx - 1024;
  int bh = id >> 4, b = bh >> 3, h = bh & 7;
  int j0 = (id & 15) * 64;
  const float s = 127.0f / __uint_as_float(scal[2]);
  int t = threadIdx.x;
  int j = t >> 2, dh0 = (t & 3) << 4;
  const float* src = kvf + (size_t)(b * MK + j0 + j) * 1024 + 512 + h * DH + dh0;
#pragma unroll
  for (int i = 0; i < 16; i += 4) {
    float4 v = *(const float4*)(src + i);
    int a0 = __float2int_rn(v.x * s), a1 = __float2int_rn(v.y * s);
    int a2 = __float2int_rn(v.z * s), a3 = __float2int_rn(v.w * s);
    tile[dh0 + i + 0][j] = (int8_t)max(-128, min(127, a0));
    tile[dh0 + i + 1][j] = (int8_t)max(-128, min(127, a1));
    tile[dh0 + i + 2][j] = (int8_t)max(-128, min(127, a2));
    tile[dh0 + i + 3][j] = (int8_t)max(-128, min(127, a3));
  }
  __syncthreads();
  int dh = t >> 2, jb = (t & 3) << 4;
  v4i val = *(const v4i*)(&tile[dh][jb]);
  *(v4i*)(v8t + (size_t)(bh * DH + dh) * MK + j0 + jb) = val;
}

__device__ __forceinline__ v4i quant_pack16(const float* p, float s) {
  v4i out;
#pragma unroll
  for (int q = 0; q < 4; ++q) {
    float4 v = *(const float4*)(p + q * 4);
    int a0 = __float2int_rn(v.x * s), a1 = __float2int_rn(v.y * s);
    int a2 = __float2int_rn(v.z * s), a3 = __float2int_rn(v.w * s);
    a0 = max(-128, min(127, a0)); a1 = max(-128, min(127, a1));
    a2 = max(-128, min(127, a2)); a3 = max(-128, min(127, a3));
    out[q] = (int)((unsigned)(a0 & 255) | ((unsigned)(a1 & 255) << 8) |
                   ((unsigned)(a2 & 255) << 16) | ((unsigned)(a3 & 255) << 24));
  }
  return out;
}

// pass 1 (r8-proven): double-buffered kbuf -> ONE barrier per tile; staging
// ds_writes moved to end of compute (overlap), global prefetch covered by
// full tile. z summation tree unchanged -> bit-identical invz.
__global__ __launch_bounds__(256, 4) void k_pass1(
    const float* __restrict__ qf, int8_t* __restrict__ q8,
    const int8_t* __restrict__ k8,
    float* __restrict__ invz, unsigned* __restrict__ scal) {
  __shared__ __align__(16) int8_t kbuf[2][128 * 72];
  __shared__ float mared[4];
  int bh = blockIdx.y, b = bh >> 3, h = bh & 7;
  int wave = threadIdx.x >> 6, lane = threadIdx.x & 63;
  int l15 = lane & 15, g = lane >> 4;
  int row0 = blockIdx.x * 64;
  int myrow = row0 + wave * 16 + l15;
  const float aq = __uint_as_float(scal[0]), ak = __uint_as_float(scal[1]);
  const float alpha2 = (aq * ak) * (0.125f / (127.0f * 127.0f)) * 1.44269504f;
  const float sq = 127.0f / aq;
  const v4i z4 = {0, 0, 0, 0};
  size_t qoff = (size_t)(b * NQ + myrow) * DMODEL + h * DH + g * 16;
  v4i qfrag = quant_pack16(qf + qoff, sq);
  *(v4i*)(q8 + qoff) = qfrag;
  const int8_t* kbase = k8 + (size_t)b * MK * DMODEL + h * DH;
  const int rs = threadIdx.x >> 2, qs = (threadIdx.x & 3) * 16;
  const int8_t* kls = kbase + (size_t)rs * DMODEL + qs;

  v4i kp0 = *(const v4i*)(kls);
  v4i kp1 = *(const v4i*)(kls + (size_t)64 * DMODEL);
  *(v4i*)(&kbuf[0][rs * 72 + qs]) = kp0;
  *(v4i*)(&kbuf[0][(rs + 64) * 72 + qs]) = kp1;

  float z[4] = {0.f, 0.f, 0.f, 0.f};
  int mi = -(1 << 30);
  for (int tile = 0; tile < 8; ++tile) {
    const int cur = tile & 1;
    __syncthreads();  // kbuf[cur] writes visible; prior reads of kbuf[cur^1] done
    if (tile < 7) {   // prefetch next tile; latency hides under compute below
      kp0 = *(const v4i*)(kls + (size_t)((tile + 1) * 128) * DMODEL);
      kp1 = *(const v4i*)(kls + (size_t)((tile + 1) * 128 + 64) * DMODEL);
    }
    float zt = z[tile >> 1];
#pragma unroll
    for (int t = 0; t < 8; ++t) {
      v4i kfrag = *(const v4i*)(&kbuf[cur][(t * 16 + l15) * 72 + g * 16]);
      v4i sa = __builtin_amdgcn_mfma_i32_16x16x64_i8(kfrag, qfrag, z4, 0, 0, 0);
      mi = max(mi, max(max(sa[0], sa[1]), max(sa[2], sa[3])));
      float e0 = __builtin_amdgcn_exp2f((float)sa[0] * alpha2);
      float e1 = __builtin_amdgcn_exp2f((float)sa[1] * alpha2);
      float e2 = __builtin_amdgcn_exp2f((float)sa[2] * alpha2);
      float e3 = __builtin_amdgcn_exp2f((float)sa[3] * alpha2);
      zt += (e0 + e1) + (e2 + e3);
    }
    z[tile >> 1] = zt;
    if (tile < 7) {   // write other buffer while peers still compute this one
      *(v4i*)(&kbuf[cur ^ 1][rs * 72 + qs]) = kp0;
      *(v4i*)(&kbuf[cur ^ 1][(rs + 64) * 72 + qs]) = kp1;
    }
  }
#pragma unroll
  for (int i = 0; i < 4; ++i) {
    z[i] += __shfl_xor(z[i], 16, 64);
    z[i] += __shfl_xor(z[i], 32, 64);
  }
  mi = max(mi, __shfl_xor(mi, 16, 64));
  mi = max(mi, __shfl_xor(mi, 32, 64));
  float zt = (z[0] + z[1]) + (z[2] + z[3]);
  float iz = 1.0f / zt;
  if (g == 0) invz[(size_t)bh * NQ + myrow] = iz;
  float ma = __builtin_amdgcn_exp2f((float)mi * alpha2) * iz;  // row softmax max
#pragma unroll
  for (int off = 1; off < 16; off <<= 1)
    ma = fmaxf(ma, __shfl_xor(ma, off, 64));
  if (lane == 0) mared[wave] = ma;
  __syncthreads();
  if (threadIdx.x == 0)
    atomicMax(scal + 3,
              __float_as_uint(fmaxf(fmaxf(mared[0], mared[1]),
                                    fmaxf(mared[2], mared[3]))));
}

// pass 2 (r8-proven): double-buffered kbuf+vbuf -> ONE barrier per tile; attn
// fragment exchange moved from LDS (albuf) to an in-register 4x4 lane-group
// transpose via shfl_xor (bytes identical -> bit-identical PV). LDS 37KB ->
// 4 blocks/CU retained. Exact int32 PV accumulation unchanged.
__global__ __launch_bounds__(256, 4) void k_pass2(
    const int8_t* __restrict__ q8, const int8_t* __restrict__ k8,
    const int8_t* __restrict__ v8t, const float* __restrict__ invz,
    const unsigned* __restrict__ scal, __bf16* __restrict__ o) {
  __shared__ __align__(16) int8_t kbuf[2][128 * 72];
  __shared__ __align__(16) int8_t vbuf[2][64 * 152];
  int bh = blockIdx.y, b = bh >> 3, h = bh & 7;
  int wave = threadIdx.x >> 6, lane = threadIdx.x & 63;
  int l15 = lane & 15, g = lane >> 4;
  int row0 = blockIdx.x * 64;
  int myrow = row0 + wave * 16 + l15;
  const float aq = __uint_as_float(scal[0]), ak = __uint_as_float(scal[1]);
  const float avv = __uint_as_float(scal[2]), izm = __uint_as_float(scal[3]);
  const float alpha2 = (aq * ak) * (0.125f / (127.0f * 127.0f)) * 1.44269504f;
  const float oscale = (izm / 127.0f) * (avv / 127.0f);
  const float MAGIC = 12582912.0f;  // 1.5 * 2^23
  const v4i z4 = {0, 0, 0, 0};

  v4i qfrag = *(const v4i*)(q8 + (size_t)(b * NQ + myrow) * DMODEL + h * DH + g * 16);
  const float lcr = __builtin_amdgcn_logf(invz[(size_t)bh * NQ + myrow] * (127.0f / izm));
  const int8_t* kbase = k8 + (size_t)b * MK * DMODEL + h * DH;
  const int8_t* vbase = v8t + (size_t)bh * DH * MK;
  const int rs = threadIdx.x >> 2, qs = (threadIdx.x & 3) * 16;
  const int vr = threadIdx.x >> 3, vq = (threadIdx.x & 7) * 16;
  const int8_t* kls = kbase + (size_t)rs * DMODEL + qs;
  const int8_t* vls = vbase + (size_t)vr * MK + vq;

  v4i kp0 = *(const v4i*)(kls);
  v4i kp1 = *(const v4i*)(kls + (size_t)64 * DMODEL);
  v4i vp0 = *(const v4i*)(vls);
  v4i vp1 = *(const v4i*)(vls + (size_t)32 * MK);
  *(v4i*)(&kbuf[0][rs * 72 + qs]) = kp0;
  *(v4i*)(&kbuf[0][(rs + 64) * 72 + qs]) = kp1;
  *(v4i*)(&vbuf[0][vr * 152 + vq]) = vp0;
  *(v4i*)(&vbuf[0][(vr + 32) * 152 + vq]) = vp1;

  v4i pacc[4] = {};
  for (int tile = 0; tile < 8; ++tile) {
    const int cur = tile & 1;
    __syncthreads();  // buf[cur] ready; peers' reads of buf[cur^1] retired
    if (tile < 7) {   // prefetch next tile; hides under QK^T + softmax + PV
      kp0 = *(const v4i*)(kls + (size_t)((tile + 1) * 128) * DMODEL);
      kp1 = *(const v4i*)(kls + (size_t)((tile + 1) * 128 + 64) * DMODEL);
      vp0 = *(const v4i*)(vls + (tile + 1) * 128);
      vp1 = *(const v4i*)(vls + (size_t)32 * MK + (tile + 1) * 128);
    }
    int w[8];
#pragma unroll
    for (int t = 0; t < 8; ++t) {
      v4i kfrag = *(const v4i*)(&kbuf[cur][(t * 16 + l15) * 72 + g * 16]);
      v4i sa = __builtin_amdgcn_mfma_i32_16x16x64_i8(kfrag, qfrag, z4, 0, 0, 0);
      float f0 = __builtin_amdgcn_exp2f(fmaf((float)sa[0], alpha2, lcr)) + MAGIC;
      float f1 = __builtin_amdgcn_exp2f(fmaf((float)sa[1], alpha2, lcr)) + MAGIC;
      float f2 = __builtin_amdgcn_exp2f(fmaf((float)sa[2], alpha2, lcr)) + MAGIC;
      float f3 = __builtin_amdgcn_exp2f(fmaf((float)sa[3], alpha2, lcr)) + MAGIC;
      w[t] = (int)((__float_as_uint(f0) & 255u) |
                   ((__float_as_uint(f1) & 255u) << 8) |
                   ((__float_as_uint(f2) & 255u) << 16) |
                   (__float_as_uint(f3) << 24));
    }
    // In-register 4x4 lane-group transpose (replaces albuf round-trip):
    // afrag[m] must be group-m's w[c*4+g]  (verified g=0 and g=1 traces).
#pragma unroll
    for (int c = 0; c < 2; ++c) {
      int wc0 = w[c * 4 + 0], wc1 = w[c * 4 + 1];
      int wc2 = w[c * 4 + 2], wc3 = w[c * 4 + 3];
      int t0 = (g & 1) ? wc0 : wc1;
      int r0 = __shfl_xor(t0, 16, 64);
      int t1 = (g & 1) ? wc2 : wc3;
      int r1 = __shfl_xor(t1, 16, 64);
      int a0 = (g & 1) ? r0 : wc0;
      int a1 = (g & 1) ? wc1 : r0;
      int a2 = (g & 1) ? r1 : wc2;
      int a3 = (g & 1) ? wc3 : r1;
      int u0 = (g & 2) ? a0 : a2;
      int s0 = __shfl_xor(u0, 32, 64);
      int u1 = (g & 2) ? a1 : a3;
      int s1 = __shfl_xor(u1, 32, 64);
      v4i afrag;
      afrag[0] = (g & 2) ? s0 : a0;
      afrag[1] = (g & 2) ? s1 : a1;
      afrag[2] = (g & 2) ? a2 : s0;
      afrag[3] = (g & 2) ? a3 : s1;
#pragma unroll
      for (int d = 0; d < 4; ++d) {
        v4i vfrag = *(const v4i*)(&vbuf[cur][(d * 16 + l15) * 152 + c * 64 + g * 16]);
        // swapped operands: D[dim][qrow] -> lane l15 = qrow, rows = dims
        pacc[d] = __builtin_amdgcn_mfma_i32_16x16x64_i8(vfrag, afrag, pacc[d], 0, 0, 0);
      }
    }
    if (tile < 7) {   // stage next tile into other buffer (overlaps peers' compute)
      *(v4i*)(&kbuf[cur ^ 1][rs * 72 + qs]) = kp0;
      *(v4i*)(&kbuf[cur ^ 1][(rs + 64) * 72 + qs]) = kp1;
      *(v4i*)(&vbuf[cur ^ 1][vr * 152 + vq]) = vp0;
      *(v4i*)(&vbuf[cur ^ 1][(vr + 32) * 152 + vq]) = vp1;
    }
  }
  // D: col(l15)=qrow, row(g*4+r)=dim-within-16 -> 4 consecutive dims per lane
  __bf16* obase = o + (size_t)(b * NQ + row0 + wave * 16 + l15) * DMODEL + h * DH;
#pragma unroll
  for (int d = 0; d < 4; ++d) {
    v4bf ov;
#pragma unroll
    for (int r = 0; r < 4; ++r)
      ov[r] = (__bf16)((float)pacc[d][r] * oscale);
    *(v4bf*)(obase + d * 16 + g * 4) = ov;
  }
}

extern "C" void kernel_launch(void* const* d_in, const int* in_sizes, int n_in,
                              void* d_out, int out_size, void* d_ws, size_t ws_size,
                              hipStream_t stream) {
  (void)in_sizes; (void)n_in; (void)out_size; (void)ws_size;
  const float* x   = (const float*)d_in[0];
  const float* ctx = (const float*)d_in[1];
  const float* Wq  = (const float*)d_in[2];
  const float* Wk  = (const float*)d_in[3];
  const float* Wv  = (const float*)d_in[4];
  const float* Wo  = (const float*)d_in[5];
  const float* bo  = (const float*)d_in[6];
  float* out = (float*)d_out;

  char* ws = (char*)d_ws;
  size_t off = 0;
  auto alloc = [&](size_t bytes) {
    char* p = ws + off;
    off += (bytes + 255) & ~(size_t)255;
    return p;
  };
  unsigned* scal = (unsigned*)alloc(16);
  __bf16* Wq_t = (__bf16*)alloc((size_t)512 * 512 * 2);
  __bf16* Wk_t = (__bf16*)alloc((size_t)512 * 768 * 2);  // contiguous with Wv_t
  __bf16* Wv_t = (__bf16*)alloc((size_t)512 * 768 * 2);
  __bf16* Wo_t = (__bf16*)alloc((size_t)512 * 512 * 2);
  __bf16* xb   = (__bf16*)alloc((size_t)BATCH * NQ * DMODEL * 2);
  __bf16* cb   = (__bf16*)alloc((size_t)BATCH * MK * DCTX * 2);
  float* qf  = (float*)alloc((size_t)BATCH * NQ * DMODEL * 4);   // later reused as o
  float* kvf = (float*)alloc((size_t)BATCH * MK * 1024 * 4);     // [2048][1024]: k | v
  int8_t* q8 = (int8_t*)alloc((size_t)BATCH * NQ * DMODEL);
  int8_t* k8 = (int8_t*)alloc((size_t)BATCH * MK * DMODEL);
  int8_t* v8t = (int8_t*)alloc((size_t)BATCH * NH * DH * MK);
  float* invz = (float*)alloc((size_t)BATCH * NH * NQ * 4);
  __bf16* o = (__bf16*)qf;  // q_f32 dead after pass1 quantizes it

  k_prep<<<4352, 256, 0, stream>>>(x, ctx, xb, cb, Wq, Wk, Wv, Wo,
                                   Wq_t, Wk_t, Wv_t, Wo_t, scal);
  k_gemm_qkv<<<512, 256, 0, stream>>>(xb, Wq_t, qf, cb, Wk_t, kvf, scal);
  k_quant_kv<<<1280, 256, 0, stream>>>(kvf, k8, v8t, scal);
  k_pass1<<<dim3(64, 16), 256, 0, stream>>>(qf, q8, k8, invz, scal);
  k_pass2<<<dim3(64, 16), 256, 0, stream>>>(q8, k8, v8t, invz, scal, o);
  k_gemm_out<<<512, 256, 0, stream>>>(o, Wo_t, out, bo);
}